// Round 5
// baseline (288.033 us; speedup 1.0000x reference)
//
#include <hip/hip_runtime.h>
#include <hip/hip_bf16.h>

#define F_IN 512
#define NCLS 64
#define SCAN_BLK 512

typedef __attribute__((ext_vector_type(8))) short short8;
typedef __attribute__((ext_vector_type(4))) float f32x4;

static __device__ __forceinline__ short bf16_of(float f) {
    __hip_bfloat16 h = __float2bfloat16(f);
    short s;
    __builtin_memcpy(&s, &h, 2);
    return s;
}
static __device__ __forceinline__ float b2f(short s) {
    unsigned u = ((unsigned)(unsigned short)s) << 16;
    float f;
    __builtin_memcpy(&f, &u, 4);
    return f;
}

// ---------------- zero cnt (replaces pathological graph-captured memset) ----------------
__global__ void zero_cnt(int* __restrict__ cnt, int n) {
    int i = blockIdx.x * blockDim.x + threadIdx.x;
    if (i < n) cnt[i] = 0;
}

// ---------------- count in-degree per dst ----------------
__global__ void deg_count(const int* __restrict__ dst, int* __restrict__ cnt, int e) {
    int i = blockIdx.x * blockDim.x + threadIdx.x;
    if (i < e) atomicAdd(&cnt[dst[i]], 1);
}

// ---------------- exclusive scan (3 kernels); scan1 also emits dinv ----------------
__global__ __launch_bounds__(SCAN_BLK) void scan1(const int* __restrict__ cnt,
                                                  int* __restrict__ off,
                                                  int* __restrict__ partials,
                                                  float* __restrict__ dinv, int n) {
    __shared__ int s[SCAN_BLK];
    int tid = threadIdx.x;
    int i = blockIdx.x * SCAN_BLK + tid;
    int v = (i < n) ? cnt[i] : 0;
    if (i < n) dinv[i] = rsqrtf(1.0f + (float)v);
    s[tid] = v;
    __syncthreads();
#pragma unroll
    for (int d = 1; d < SCAN_BLK; d <<= 1) {
        int t = (tid >= d) ? s[tid - d] : 0;
        __syncthreads();
        s[tid] += t;
        __syncthreads();
    }
    if (i < n) off[i] = s[tid] - v;  // exclusive
    if (tid == SCAN_BLK - 1) partials[blockIdx.x] = s[tid];
}

__global__ __launch_bounds__(256) void scan2(int* __restrict__ partials, int p) {
    __shared__ int s[256];
    int tid = threadIdx.x;
    int v = (tid < p) ? partials[tid] : 0;
    s[tid] = v;
    __syncthreads();
#pragma unroll
    for (int d = 1; d < 256; d <<= 1) {
        int t = (tid >= d) ? s[tid - d] : 0;
        __syncthreads();
        s[tid] += t;
        __syncthreads();
    }
    if (tid < p) partials[tid] = s[tid] - v;  // exclusive
}

// off[i] += block partial; cursor[i] = off[i]  (absolute write cursor, no zeroing needed)
__global__ void scan3(int* __restrict__ off, const int* __restrict__ partials,
                      int* __restrict__ cursor, int n) {
    int i = blockIdx.x * blockDim.x + threadIdx.x;
    if (i < n) {
        int v = off[i] + partials[i / SCAN_BLK];
        off[i] = v;
        cursor[i] = v;
    }
}

// ---------------- fill CSR edge list (cursor holds absolute positions) ----------------
__global__ void fill_csr(const int* __restrict__ src, const int* __restrict__ dst,
                         int* __restrict__ cursor, int* __restrict__ eidx, int e) {
    int i = blockIdx.x * blockDim.x + threadIdx.x;
    if (i < e) {
        int p = atomicAdd(&cursor[dst[i]], 1);
        eidx[p] = src[i];
    }
}

// ---------------- W -> bf16 B-fragment layout ----------------
__global__ void wconvert(const float* __restrict__ W, short* __restrict__ Wb) {
    int t = blockIdx.x * blockDim.x + threadIdx.x;  // 4096 threads
    if (t >= 4096) return;
    int c = t >> 10;
    int kk = (t >> 6) & 15;
    int l = t & 63;
    short8 v;
#pragma unroll
    for (int j = 0; j < 8; ++j) {
        v[j] = bf16_of(W[(size_t)(kk * 32 + (l >> 4) * 8 + j) * NCLS + c * 16 + (l & 15)]);
    }
    reinterpret_cast<short8*>(Wb)[t] = v;
}

// ---------------- MFMA GEMM: g = bf16((x @ W) * dinv[row]) ----------------
__global__ __launch_bounds__(256) void gemm_mfma(const float* __restrict__ x,
                                                 const short* __restrict__ Wb,
                                                 const float* __restrict__ dinv,
                                                 short* __restrict__ g, int n) {
    const int wave = threadIdx.x >> 6;
    const int lane = threadIdx.x & 63;
    const int rowTile = blockIdx.x * 64 + wave * 16;

    int arow = rowTile + (lane & 15);
    if (arow > n - 1) arow = n - 1;  // tail clamp (stores are guarded)
    const float* xr = x + (size_t)arow * F_IN + ((lane >> 4) * 8);

    const short8* wb8 = reinterpret_cast<const short8*>(Wb);

    f32x4 acc0 = {0.f, 0.f, 0.f, 0.f};
    f32x4 acc1 = {0.f, 0.f, 0.f, 0.f};
    f32x4 acc2 = {0.f, 0.f, 0.f, 0.f};
    f32x4 acc3 = {0.f, 0.f, 0.f, 0.f};

#pragma unroll 4
    for (int kk = 0; kk < 16; ++kk) {
        float4 f0 = *reinterpret_cast<const float4*>(xr + kk * 32);
        float4 f1 = *reinterpret_cast<const float4*>(xr + kk * 32 + 4);
        short8 a;
        a[0] = bf16_of(f0.x); a[1] = bf16_of(f0.y);
        a[2] = bf16_of(f0.z); a[3] = bf16_of(f0.w);
        a[4] = bf16_of(f1.x); a[5] = bf16_of(f1.y);
        a[6] = bf16_of(f1.z); a[7] = bf16_of(f1.w);
        short8 b0 = wb8[(0 * 16 + kk) * 64 + lane];
        short8 b1 = wb8[(1 * 16 + kk) * 64 + lane];
        short8 b2 = wb8[(2 * 16 + kk) * 64 + lane];
        short8 b3 = wb8[(3 * 16 + kk) * 64 + lane];
        acc0 = __builtin_amdgcn_mfma_f32_16x16x32_bf16(a, b0, acc0, 0, 0, 0);
        acc1 = __builtin_amdgcn_mfma_f32_16x16x32_bf16(a, b1, acc1, 0, 0, 0);
        acc2 = __builtin_amdgcn_mfma_f32_16x16x32_bf16(a, b2, acc2, 0, 0, 0);
        acc3 = __builtin_amdgcn_mfma_f32_16x16x32_bf16(a, b3, acc3, 0, 0, 0);
    }

    const int col = lane & 15;
    const int rbase = rowTile + (lane >> 4) * 4;
#pragma unroll
    for (int j = 0; j < 4; ++j) {
        int r = rbase + j;
        if (r < n) {
            float dv = dinv[r];
            short* go = g + (size_t)r * NCLS + col;
            go[0]  = bf16_of(acc0[j] * dv);
            go[16] = bf16_of(acc1[j] * dv);
            go[32] = bf16_of(acc2[j] * dv);
            go[48] = bf16_of(acc3[j] * dv);
        }
    }
}

// ---------------- fused gather + bias + log_softmax ----------------
// 8 nodes per wave: 8-lane sub-group per node; lane handles 8 channels (short8 = 16B).
__global__ __launch_bounds__(256) void aggregate(const short* __restrict__ g,
                                                 const float* __restrict__ dinv,
                                                 const float* __restrict__ b,
                                                 const int* __restrict__ off,
                                                 const int* __restrict__ eidx,
                                                 float* __restrict__ out, int n, int e) {
    const int wave = threadIdx.x >> 6;
    const int lane = threadIdx.x & 63;
    const int grp = lane >> 3;   // node sub-group 0..7
    const int li = lane & 7;     // covers channels li*8 .. li*8+7
    const int node = (blockIdx.x * 4 + wave) * 8 + grp;
    if (node >= n) return;

    const int s0 = off[node];
    const int s1 = (node + 1 < n) ? off[node + 1] : e;

    const short8* g8 = reinterpret_cast<const short8*>(g);  // 8 short8 per row

    float acc[8];
    {
        short8 v = g8[(size_t)node * 8 + li];
#pragma unroll
        for (int c = 0; c < 8; ++c) acc[c] = b2f(v[c]);
    }

    int t = s0;
    for (; t + 4 <= s1; t += 4) {
        int sa = eidx[t];
        int sb = eidx[t + 1];
        int sc = eidx[t + 2];
        int sd = eidx[t + 3];
        short8 va = g8[(size_t)sa * 8 + li];
        short8 vb = g8[(size_t)sb * 8 + li];
        short8 vc = g8[(size_t)sc * 8 + li];
        short8 vd = g8[(size_t)sd * 8 + li];
#pragma unroll
        for (int c = 0; c < 8; ++c)
            acc[c] += (b2f(va[c]) + b2f(vb[c])) + (b2f(vc[c]) + b2f(vd[c]));
    }
    for (; t < s1; ++t) {
        int sa = eidx[t];
        short8 va = g8[(size_t)sa * 8 + li];
#pragma unroll
        for (int c = 0; c < 8; ++c) acc[c] += b2f(va[c]);
    }

    const float dn = dinv[node];
    const float4 b0 = reinterpret_cast<const float4*>(b)[li * 2];
    const float4 b1 = reinterpret_cast<const float4*>(b)[li * 2 + 1];
    float v[8];
    v[0] = acc[0] * dn + b0.x; v[1] = acc[1] * dn + b0.y;
    v[2] = acc[2] * dn + b0.z; v[3] = acc[3] * dn + b0.w;
    v[4] = acc[4] * dn + b1.x; v[5] = acc[5] * dn + b1.y;
    v[6] = acc[6] * dn + b1.z; v[7] = acc[7] * dn + b1.w;

    float m = v[0];
#pragma unroll
    for (int c = 1; c < 8; ++c) m = fmaxf(m, v[c]);
#pragma unroll
    for (int o = 1; o < 8; o <<= 1) m = fmaxf(m, __shfl_xor(m, o));

    float ex = 0.f;
#pragma unroll
    for (int c = 0; c < 8; ++c) ex += __expf(v[c] - m);
#pragma unroll
    for (int o = 1; o < 8; o <<= 1) ex += __shfl_xor(ex, o);
    const float lg = m + __logf(ex);

    float4 r0, r1;
    r0.x = v[0] - lg; r0.y = v[1] - lg; r0.z = v[2] - lg; r0.w = v[3] - lg;
    r1.x = v[4] - lg; r1.y = v[5] - lg; r1.z = v[6] - lg; r1.w = v[7] - lg;
    float4* o4 = reinterpret_cast<float4*>(out + (size_t)node * NCLS);
    o4[li * 2] = r0;
    o4[li * 2 + 1] = r1;
}

extern "C" void kernel_launch(void* const* d_in, const int* in_sizes, int n_in,
                              void* d_out, int out_size, void* d_ws, size_t ws_size,
                              hipStream_t stream) {
    const float* x = (const float*)d_in[0];       // [N, 512]
    const float* W = (const float*)d_in[1];       // [512, 64]
    const float* b = (const float*)d_in[2];       // [64]
    const int* edge_index = (const int*)d_in[3];  // [2, E]

    const int N = in_sizes[0] / F_IN;
    const int E = in_sizes[3] / 2;
    const int* src = edge_index;
    const int* dst = edge_index + E;

    float* out = (float*)d_out;  // [N, 64]

    // workspace layout (16B-aligned pieces first)
    char* ws = (char*)d_ws;
    short* g      = (short*)ws;  ws += (size_t)N * NCLS * 2;   // 12.8 MB bf16
    short* Wb     = (short*)ws;  ws += 4096 * 16;              // 64 KB
    float* dinv   = (float*)ws;  ws += (size_t)N * 4;
    int*   cnt    = (int*)ws;    ws += (size_t)N * 4;
    int*   cursor = (int*)ws;    ws += (size_t)N * 4;
    int*   off    = (int*)ws;    ws += (size_t)(N + 4) * 4;
    int*   parts  = (int*)ws;    ws += 1024 * 4;
    int*   eidx   = (int*)ws;    // E ints

    const int nScanBlocks = (N + SCAN_BLK - 1) / SCAN_BLK;

    zero_cnt<<<(N + 255) / 256, 256, 0, stream>>>(cnt, N);

    deg_count<<<(E + 255) / 256, 256, 0, stream>>>(dst, cnt, E);

    scan1<<<nScanBlocks, SCAN_BLK, 0, stream>>>(cnt, off, parts, dinv, N);
    scan2<<<1, 256, 0, stream>>>(parts, nScanBlocks);
    scan3<<<(N + 255) / 256, 256, 0, stream>>>(off, parts, cursor, N);

    fill_csr<<<(E + 255) / 256, 256, 0, stream>>>(src, dst, cursor, eidx, E);

    wconvert<<<16, 256, 0, stream>>>(W, Wb);

    gemm_mfma<<<(N + 63) / 64, 256, 0, stream>>>(x, Wb, dinv, g, N);

    aggregate<<<(N + 31) / 32, 256, 0, stream>>>(g, dinv, b, off, eidx, out, N, E);
}

// Round 6
// 189.564 us; speedup vs baseline: 1.5195x; 1.5195x over previous
//
#include <hip/hip_runtime.h>
#include <hip/hip_bf16.h>

#define F_IN 512
#define NCLS 64
#define SCAN_BLK 512

typedef __attribute__((ext_vector_type(8))) short short8;
typedef __attribute__((ext_vector_type(4))) float f32x4;

static __device__ __forceinline__ short bf16_of(float f) {
    __hip_bfloat16 h = __float2bfloat16(f);
    short s;
    __builtin_memcpy(&s, &h, 2);
    return s;
}
static __device__ __forceinline__ float b2f(short s) {
    unsigned u = ((unsigned)(unsigned short)s) << 16;
    float f;
    __builtin_memcpy(&f, &u, 4);
    return f;
}

// ---------------- zero cnt ----------------
__global__ void zero_cnt(int* __restrict__ cnt, int n) {
    int i = blockIdx.x * blockDim.x + threadIdx.x;
    if (i < n) cnt[i] = 0;
}

// ---------------- count in-degree per dst AND capture per-edge rank ----------------
// The single contended-atomic pass: rank[i] = old count. fill_csr then needs no atomics.
__global__ void deg_count(const int* __restrict__ dst, int* __restrict__ cnt,
                          int* __restrict__ rank, int e) {
    int i = blockIdx.x * blockDim.x + threadIdx.x;
    if (i < e) rank[i] = atomicAdd(&cnt[dst[i]], 1);
}

// ---------------- exclusive scan (3 kernels); scan1 also emits dinv ----------------
__global__ __launch_bounds__(SCAN_BLK) void scan1(const int* __restrict__ cnt,
                                                  int* __restrict__ off,
                                                  int* __restrict__ partials,
                                                  float* __restrict__ dinv, int n) {
    __shared__ int s[SCAN_BLK];
    int tid = threadIdx.x;
    int i = blockIdx.x * SCAN_BLK + tid;
    int v = (i < n) ? cnt[i] : 0;
    if (i < n) dinv[i] = rsqrtf(1.0f + (float)v);
    s[tid] = v;
    __syncthreads();
#pragma unroll
    for (int d = 1; d < SCAN_BLK; d <<= 1) {
        int t = (tid >= d) ? s[tid - d] : 0;
        __syncthreads();
        s[tid] += t;
        __syncthreads();
    }
    if (i < n) off[i] = s[tid] - v;  // exclusive
    if (tid == SCAN_BLK - 1) partials[blockIdx.x] = s[tid];
}

__global__ __launch_bounds__(256) void scan2(int* __restrict__ partials, int p) {
    __shared__ int s[256];
    int tid = threadIdx.x;
    int v = (tid < p) ? partials[tid] : 0;
    s[tid] = v;
    __syncthreads();
#pragma unroll
    for (int d = 1; d < 256; d <<= 1) {
        int t = (tid >= d) ? s[tid - d] : 0;
        __syncthreads();
        s[tid] += t;
        __syncthreads();
    }
    if (tid < p) partials[tid] = s[tid] - v;  // exclusive
}

// off[i] += block partial; also write off[n] = e sentinel
__global__ void scan3(int* __restrict__ off, const int* __restrict__ partials,
                      int n, int e) {
    int i = blockIdx.x * blockDim.x + threadIdx.x;
    if (i < n) off[i] += partials[i / SCAN_BLK];
    if (i == 0) off[n] = e;
}

// ---------------- fill CSR edge list — NO atomics ----------------
__global__ void fill_csr(const int* __restrict__ src, const int* __restrict__ dst,
                         const int* __restrict__ off, const int* __restrict__ rank,
                         int* __restrict__ eidx, int e) {
    int i = blockIdx.x * blockDim.x + threadIdx.x;
    if (i < e) eidx[off[dst[i]] + rank[i]] = src[i];
}

// ---------------- W -> bf16 B-fragment layout ----------------
__global__ void wconvert(const float* __restrict__ W, short* __restrict__ Wb) {
    int t = blockIdx.x * blockDim.x + threadIdx.x;  // 4096 threads
    if (t >= 4096) return;
    int c = t >> 10;
    int kk = (t >> 6) & 15;
    int l = t & 63;
    short8 v;
#pragma unroll
    for (int j = 0; j < 8; ++j) {
        v[j] = bf16_of(W[(size_t)(kk * 32 + (l >> 4) * 8 + j) * NCLS + c * 16 + (l & 15)]);
    }
    reinterpret_cast<short8*>(Wb)[t] = v;
}

// ---------------- MFMA GEMM: g = bf16((x @ W) * dinv[row]) ----------------
__global__ __launch_bounds__(256) void gemm_mfma(const float* __restrict__ x,
                                                 const short* __restrict__ Wb,
                                                 const float* __restrict__ dinv,
                                                 short* __restrict__ g, int n) {
    const int wave = threadIdx.x >> 6;
    const int lane = threadIdx.x & 63;
    const int rowTile = blockIdx.x * 64 + wave * 16;

    int arow = rowTile + (lane & 15);
    if (arow > n - 1) arow = n - 1;  // tail clamp (stores are guarded)
    const float* xr = x + (size_t)arow * F_IN + ((lane >> 4) * 8);

    const short8* wb8 = reinterpret_cast<const short8*>(Wb);

    f32x4 acc0 = {0.f, 0.f, 0.f, 0.f};
    f32x4 acc1 = {0.f, 0.f, 0.f, 0.f};
    f32x4 acc2 = {0.f, 0.f, 0.f, 0.f};
    f32x4 acc3 = {0.f, 0.f, 0.f, 0.f};

#pragma unroll 4
    for (int kk = 0; kk < 16; ++kk) {
        float4 f0 = *reinterpret_cast<const float4*>(xr + kk * 32);
        float4 f1 = *reinterpret_cast<const float4*>(xr + kk * 32 + 4);
        short8 a;
        a[0] = bf16_of(f0.x); a[1] = bf16_of(f0.y);
        a[2] = bf16_of(f0.z); a[3] = bf16_of(f0.w);
        a[4] = bf16_of(f1.x); a[5] = bf16_of(f1.y);
        a[6] = bf16_of(f1.z); a[7] = bf16_of(f1.w);
        short8 b0 = wb8[(0 * 16 + kk) * 64 + lane];
        short8 b1 = wb8[(1 * 16 + kk) * 64 + lane];
        short8 b2 = wb8[(2 * 16 + kk) * 64 + lane];
        short8 b3 = wb8[(3 * 16 + kk) * 64 + lane];
        acc0 = __builtin_amdgcn_mfma_f32_16x16x32_bf16(a, b0, acc0, 0, 0, 0);
        acc1 = __builtin_amdgcn_mfma_f32_16x16x32_bf16(a, b1, acc1, 0, 0, 0);
        acc2 = __builtin_amdgcn_mfma_f32_16x16x32_bf16(a, b2, acc2, 0, 0, 0);
        acc3 = __builtin_amdgcn_mfma_f32_16x16x32_bf16(a, b3, acc3, 0, 0, 0);
    }

    const int col = lane & 15;
    const int rbase = rowTile + (lane >> 4) * 4;
#pragma unroll
    for (int j = 0; j < 4; ++j) {
        int r = rbase + j;
        if (r < n) {
            float dv = dinv[r];
            short* go = g + (size_t)r * NCLS + col;
            go[0]  = bf16_of(acc0[j] * dv);
            go[16] = bf16_of(acc1[j] * dv);
            go[32] = bf16_of(acc2[j] * dv);
            go[48] = bf16_of(acc3[j] * dv);
        }
    }
}

// ---------------- fused gather + bias + log_softmax ----------------
// 8 nodes per wave: 8-lane sub-group per node; lane handles 8 channels (short8 = 16B).
__global__ __launch_bounds__(256) void aggregate(const short* __restrict__ g,
                                                 const float* __restrict__ dinv,
                                                 const float* __restrict__ b,
                                                 const int* __restrict__ off,
                                                 const int* __restrict__ eidx,
                                                 float* __restrict__ out, int n) {
    const int wave = threadIdx.x >> 6;
    const int lane = threadIdx.x & 63;
    const int grp = lane >> 3;   // node sub-group 0..7
    const int li = lane & 7;     // covers channels li*8 .. li*8+7
    const int node = (blockIdx.x * 4 + wave) * 8 + grp;
    if (node >= n) return;

    const int s0 = off[node];
    const int s1 = off[node + 1];

    const short8* g8 = reinterpret_cast<const short8*>(g);  // 8 short8 per row

    float acc[8];
    {
        short8 v = g8[(size_t)node * 8 + li];
#pragma unroll
        for (int c = 0; c < 8; ++c) acc[c] = b2f(v[c]);
    }

    int t = s0;
    for (; t + 4 <= s1; t += 4) {
        int sa = eidx[t];
        int sb = eidx[t + 1];
        int sc = eidx[t + 2];
        int sd = eidx[t + 3];
        short8 va = g8[(size_t)sa * 8 + li];
        short8 vb = g8[(size_t)sb * 8 + li];
        short8 vc = g8[(size_t)sc * 8 + li];
        short8 vd = g8[(size_t)sd * 8 + li];
#pragma unroll
        for (int c = 0; c < 8; ++c)
            acc[c] += (b2f(va[c]) + b2f(vb[c])) + (b2f(vc[c]) + b2f(vd[c]));
    }
    for (; t < s1; ++t) {
        int sa = eidx[t];
        short8 va = g8[(size_t)sa * 8 + li];
#pragma unroll
        for (int c = 0; c < 8; ++c) acc[c] += b2f(va[c]);
    }

    const float dn = dinv[node];
    const float4 b0 = reinterpret_cast<const float4*>(b)[li * 2];
    const float4 b1 = reinterpret_cast<const float4*>(b)[li * 2 + 1];
    float v[8];
    v[0] = acc[0] * dn + b0.x; v[1] = acc[1] * dn + b0.y;
    v[2] = acc[2] * dn + b0.z; v[3] = acc[3] * dn + b0.w;
    v[4] = acc[4] * dn + b1.x; v[5] = acc[5] * dn + b1.y;
    v[6] = acc[6] * dn + b1.z; v[7] = acc[7] * dn + b1.w;

    float m = v[0];
#pragma unroll
    for (int c = 1; c < 8; ++c) m = fmaxf(m, v[c]);
#pragma unroll
    for (int o = 1; o < 8; o <<= 1) m = fmaxf(m, __shfl_xor(m, o));

    float ex = 0.f;
#pragma unroll
    for (int c = 0; c < 8; ++c) ex += __expf(v[c] - m);
#pragma unroll
    for (int o = 1; o < 8; o <<= 1) ex += __shfl_xor(ex, o);
    const float lg = m + __logf(ex);

    float4 r0, r1;
    r0.x = v[0] - lg; r0.y = v[1] - lg; r0.z = v[2] - lg; r0.w = v[3] - lg;
    r1.x = v[4] - lg; r1.y = v[5] - lg; r1.z = v[6] - lg; r1.w = v[7] - lg;
    float4* o4 = reinterpret_cast<float4*>(out + (size_t)node * NCLS);
    o4[li * 2] = r0;
    o4[li * 2 + 1] = r1;
}

extern "C" void kernel_launch(void* const* d_in, const int* in_sizes, int n_in,
                              void* d_out, int out_size, void* d_ws, size_t ws_size,
                              hipStream_t stream) {
    const float* x = (const float*)d_in[0];       // [N, 512]
    const float* W = (const float*)d_in[1];       // [512, 64]
    const float* b = (const float*)d_in[2];       // [64]
    const int* edge_index = (const int*)d_in[3];  // [2, E]

    const int N = in_sizes[0] / F_IN;
    const int E = in_sizes[3] / 2;
    const int* src = edge_index;
    const int* dst = edge_index + E;

    float* out = (float*)d_out;  // [N, 64]

    // workspace layout (16B-aligned pieces first)
    char* ws = (char*)d_ws;
    short* g      = (short*)ws;  ws += (size_t)N * NCLS * 2;   // 12.8 MB bf16
    short* Wb     = (short*)ws;  ws += 4096 * 16;              // 64 KB
    float* dinv   = (float*)ws;  ws += (size_t)N * 4;
    int*   cnt    = (int*)ws;    ws += (size_t)N * 4;
    int*   off    = (int*)ws;    ws += (size_t)(N + 4) * 4;
    int*   parts  = (int*)ws;    ws += 1024 * 4;
    int*   rank   = (int*)ws;    ws += (size_t)E * 4;          // 6.4 MB
    int*   eidx   = (int*)ws;    // E ints

    const int nScanBlocks = (N + SCAN_BLK - 1) / SCAN_BLK;

    zero_cnt<<<(N + 255) / 256, 256, 0, stream>>>(cnt, N);

    deg_count<<<(E + 255) / 256, 256, 0, stream>>>(dst, cnt, rank, E);

    scan1<<<nScanBlocks, SCAN_BLK, 0, stream>>>(cnt, off, parts, dinv, N);
    scan2<<<1, 256, 0, stream>>>(parts, nScanBlocks);
    scan3<<<(N + 255) / 256, 256, 0, stream>>>(off, parts, N, E);

    fill_csr<<<(E + 255) / 256, 256, 0, stream>>>(src, dst, off, rank, eidx, E);

    wconvert<<<16, 256, 0, stream>>>(W, Wb);

    gemm_mfma<<<(N + 63) / 64, 256, 0, stream>>>(x, Wb, dinv, g, N);

    aggregate<<<(N + 31) / 32, 256, 0, stream>>>(g, dinv, b, off, eidx, out, N);
}

// Round 7
// 186.546 us; speedup vs baseline: 1.5440x; 1.0162x over previous
//
#include <hip/hip_runtime.h>
#include <hip/hip_bf16.h>

#define F_IN 512
#define NCLS 64
#define SCAN_BLK 512

typedef __attribute__((ext_vector_type(8))) short short8;
typedef __attribute__((ext_vector_type(4))) float f32x4;

static __device__ __forceinline__ short bf16_of(float f) {
    __hip_bfloat16 h = __float2bfloat16(f);
    short s;
    __builtin_memcpy(&s, &h, 2);
    return s;
}
static __device__ __forceinline__ float b2f(short s) {
    unsigned u = ((unsigned)(unsigned short)s) << 16;
    float f;
    __builtin_memcpy(&f, &u, 4);
    return f;
}

// ---------------- prelude: wconvert (blocks 0..15) + zero cnt (rest) ----------------
__global__ __launch_bounds__(256) void prelude(const float* __restrict__ W,
                                               short* __restrict__ Wb,
                                               int* __restrict__ cnt, int n) {
    const int bid = blockIdx.x;
    if (bid < 16) {
        int t = bid * 256 + threadIdx.x;  // 4096 total
        int c = t >> 10;
        int kk = (t >> 6) & 15;
        int l = t & 63;
        short8 v;
#pragma unroll
        for (int j = 0; j < 8; ++j) {
            v[j] = bf16_of(W[(size_t)(kk * 32 + (l >> 4) * 8 + j) * NCLS + c * 16 + (l & 15)]);
        }
        reinterpret_cast<short8*>(Wb)[t] = v;
    } else {
        int i = (bid - 16) * 256 + threadIdx.x;
        if (i < n) cnt[i] = 0;
    }
}

// ---------------- megaA: interleaved {MFMA GEMM (unscaled)} + {deg_count+rank} ----------------
// even blocks -> gemm tile, odd blocks -> degree counting (4 edges/thread, int4).
__global__ __launch_bounds__(256) void megaA(const float* __restrict__ x,
                                             const short* __restrict__ Wb,
                                             short* __restrict__ g, int n,
                                             const int* __restrict__ dst,
                                             int* __restrict__ cnt,
                                             unsigned short* __restrict__ rank, int e,
                                             int gemmBlocks, int degBlocks) {
    const int bid = blockIdx.x;
    const int m2 = 2 * (gemmBlocks < degBlocks ? gemmBlocks : degBlocks);
    int role, idx;
    if (bid < m2) { role = bid & 1; idx = bid >> 1; }
    else if (gemmBlocks > degBlocks) { role = 0; idx = bid - degBlocks; }
    else { role = 1; idx = bid - gemmBlocks; }

    if (role == 1) {
        // ---- degree count + per-edge rank ----
        int base = (idx * 256 + threadIdx.x) * 4;
        if (base + 4 <= e) {
            int4 d4 = *reinterpret_cast<const int4*>(dst + base);
            ushort4 r;
            r.x = (unsigned short)atomicAdd(&cnt[d4.x], 1);
            r.y = (unsigned short)atomicAdd(&cnt[d4.y], 1);
            r.z = (unsigned short)atomicAdd(&cnt[d4.z], 1);
            r.w = (unsigned short)atomicAdd(&cnt[d4.w], 1);
            *reinterpret_cast<ushort4*>(rank + base) = r;
        } else {
            for (int i = base; i < e; ++i)
                rank[i] = (unsigned short)atomicAdd(&cnt[dst[i]], 1);
        }
        return;
    }

    // ---- gemm tile: g = bf16(x @ W), unscaled ----
    const int wave = threadIdx.x >> 6;
    const int lane = threadIdx.x & 63;
    const int rowTile = idx * 64 + wave * 16;

    int arow = rowTile + (lane & 15);
    if (arow > n - 1) arow = n - 1;  // tail clamp (stores are guarded)
    const float* xr = x + (size_t)arow * F_IN + ((lane >> 4) * 8);

    const short8* wb8 = reinterpret_cast<const short8*>(Wb);

    f32x4 acc0 = {0.f, 0.f, 0.f, 0.f};
    f32x4 acc1 = {0.f, 0.f, 0.f, 0.f};
    f32x4 acc2 = {0.f, 0.f, 0.f, 0.f};
    f32x4 acc3 = {0.f, 0.f, 0.f, 0.f};

#pragma unroll 4
    for (int kk = 0; kk < 16; ++kk) {
        float4 f0 = *reinterpret_cast<const float4*>(xr + kk * 32);
        float4 f1 = *reinterpret_cast<const float4*>(xr + kk * 32 + 4);
        short8 a;
        a[0] = bf16_of(f0.x); a[1] = bf16_of(f0.y);
        a[2] = bf16_of(f0.z); a[3] = bf16_of(f0.w);
        a[4] = bf16_of(f1.x); a[5] = bf16_of(f1.y);
        a[6] = bf16_of(f1.z); a[7] = bf16_of(f1.w);
        short8 b0 = wb8[(0 * 16 + kk) * 64 + lane];
        short8 b1 = wb8[(1 * 16 + kk) * 64 + lane];
        short8 b2 = wb8[(2 * 16 + kk) * 64 + lane];
        short8 b3 = wb8[(3 * 16 + kk) * 64 + lane];
        acc0 = __builtin_amdgcn_mfma_f32_16x16x32_bf16(a, b0, acc0, 0, 0, 0);
        acc1 = __builtin_amdgcn_mfma_f32_16x16x32_bf16(a, b1, acc1, 0, 0, 0);
        acc2 = __builtin_amdgcn_mfma_f32_16x16x32_bf16(a, b2, acc2, 0, 0, 0);
        acc3 = __builtin_amdgcn_mfma_f32_16x16x32_bf16(a, b3, acc3, 0, 0, 0);
    }

    const int col = lane & 15;
    const int rbase = rowTile + (lane >> 4) * 4;
#pragma unroll
    for (int j = 0; j < 4; ++j) {
        int r = rbase + j;
        if (r < n) {
            short* go = g + (size_t)r * NCLS + col;
            go[0]  = bf16_of(acc0[j]);
            go[16] = bf16_of(acc1[j]);
            go[32] = bf16_of(acc2[j]);
            go[48] = bf16_of(acc3[j]);
        }
    }
}

// ---------------- scan1: block-local exclusive scan + dinv; off[n] = last-block inclusive ----------------
__global__ __launch_bounds__(SCAN_BLK) void scan1(const int* __restrict__ cnt,
                                                  int* __restrict__ off,
                                                  int* __restrict__ partials,
                                                  float* __restrict__ dinv, int n) {
    __shared__ int s[SCAN_BLK];
    int tid = threadIdx.x;
    int i = blockIdx.x * SCAN_BLK + tid;
    int v = (i < n) ? cnt[i] : 0;
    if (i < n) dinv[i] = rsqrtf(1.0f + (float)v);
    s[tid] = v;
    __syncthreads();
#pragma unroll
    for (int d = 1; d < SCAN_BLK; d <<= 1) {
        int t = (tid >= d) ? s[tid - d] : 0;
        __syncthreads();
        s[tid] += t;
        __syncthreads();
    }
    if (i < n) off[i] = s[tid] - v;       // block-local exclusive
    if (i == n - 1) off[n] = s[tid];      // block-local inclusive sentinel
    if (tid == SCAN_BLK - 1) partials[blockIdx.x] = s[tid];
}

__global__ __launch_bounds__(256) void scan2(int* __restrict__ partials, int p) {
    __shared__ int s[256];
    int tid = threadIdx.x;
    int v = (tid < p) ? partials[tid] : 0;
    s[tid] = v;
    __syncthreads();
#pragma unroll
    for (int d = 1; d < 256; d <<= 1) {
        int t = (tid >= d) ? s[tid - d] : 0;
        __syncthreads();
        s[tid] += t;
        __syncthreads();
    }
    if (tid < p) partials[tid] = s[tid] - v;  // exclusive
}

// ---------------- fill CSR edge list — NO atomics, 4 edges/thread ----------------
__global__ __launch_bounds__(256) void fill_csr(const int* __restrict__ src,
                                                const int* __restrict__ dst,
                                                const int* __restrict__ off,
                                                const int* __restrict__ parts,
                                                const unsigned short* __restrict__ rank,
                                                int* __restrict__ eidx, int e) {
    int base = (blockIdx.x * 256 + threadIdx.x) * 4;
    if (base + 4 <= e) {
        int4 s4 = *reinterpret_cast<const int4*>(src + base);
        int4 d4 = *reinterpret_cast<const int4*>(dst + base);
        ushort4 r4 = *reinterpret_cast<const ushort4*>(rank + base);
        eidx[off[d4.x] + parts[d4.x >> 9] + r4.x] = s4.x;
        eidx[off[d4.y] + parts[d4.y >> 9] + r4.y] = s4.y;
        eidx[off[d4.z] + parts[d4.z >> 9] + r4.z] = s4.z;
        eidx[off[d4.w] + parts[d4.w >> 9] + r4.w] = s4.w;
    } else {
        for (int i = base; i < e; ++i)
            eidx[off[dst[i]] + parts[dst[i] >> 9] + rank[i]] = src[i];
    }
}

// ---------------- fused gather + per-edge dinv[src] + bias + log_softmax ----------------
// 8 nodes per wave: 8-lane sub-group per node; lane handles 8 channels (short8 = 16B).
__global__ __launch_bounds__(256) void aggregate(const short* __restrict__ g,
                                                 const float* __restrict__ dinv,
                                                 const float* __restrict__ b,
                                                 const int* __restrict__ off,
                                                 const int* __restrict__ parts,
                                                 const int* __restrict__ eidx,
                                                 float* __restrict__ out, int n) {
    const int wave = threadIdx.x >> 6;
    const int lane = threadIdx.x & 63;
    const int grp = lane >> 3;   // node sub-group 0..7
    const int li = lane & 7;     // covers channels li*8 .. li*8+7
    const int node = (blockIdx.x * 4 + wave) * 8 + grp;
    if (node >= n) return;

    const int s0 = off[node] + parts[node >> 9];
    const int np1 = node + 1;
    const int s1 = off[np1] + parts[(np1 == n ? n - 1 : np1) >> 9];

    const short8* g8 = reinterpret_cast<const short8*>(g);  // 8 short8 per row
    const float dn = dinv[node];

    float acc[8];
    {
        short8 v = g8[(size_t)node * 8 + li];
#pragma unroll
        for (int c = 0; c < 8; ++c) acc[c] = b2f(v[c]) * dn;  // self-loop: g*dinv
    }

    int t = s0;
    for (; t + 4 <= s1; t += 4) {
        int sa = eidx[t];
        int sb = eidx[t + 1];
        int sc = eidx[t + 2];
        int sd = eidx[t + 3];
        float da = dinv[sa], db = dinv[sb], dc = dinv[sc], dd = dinv[sd];
        short8 va = g8[(size_t)sa * 8 + li];
        short8 vb = g8[(size_t)sb * 8 + li];
        short8 vc = g8[(size_t)sc * 8 + li];
        short8 vd = g8[(size_t)sd * 8 + li];
#pragma unroll
        for (int c = 0; c < 8; ++c)
            acc[c] += (b2f(va[c]) * da + b2f(vb[c]) * db) + (b2f(vc[c]) * dc + b2f(vd[c]) * dd);
    }
    for (; t < s1; ++t) {
        int sa = eidx[t];
        float da = dinv[sa];
        short8 va = g8[(size_t)sa * 8 + li];
#pragma unroll
        for (int c = 0; c < 8; ++c) acc[c] += b2f(va[c]) * da;
    }

    const float4 b0 = reinterpret_cast<const float4*>(b)[li * 2];
    const float4 b1 = reinterpret_cast<const float4*>(b)[li * 2 + 1];
    float v[8];
    v[0] = acc[0] * dn + b0.x; v[1] = acc[1] * dn + b0.y;
    v[2] = acc[2] * dn + b0.z; v[3] = acc[3] * dn + b0.w;
    v[4] = acc[4] * dn + b1.x; v[5] = acc[5] * dn + b1.y;
    v[6] = acc[6] * dn + b1.z; v[7] = acc[7] * dn + b1.w;

    float m = v[0];
#pragma unroll
    for (int c = 1; c < 8; ++c) m = fmaxf(m, v[c]);
#pragma unroll
    for (int o = 1; o < 8; o <<= 1) m = fmaxf(m, __shfl_xor(m, o));

    float ex = 0.f;
#pragma unroll
    for (int c = 0; c < 8; ++c) ex += __expf(v[c] - m);
#pragma unroll
    for (int o = 1; o < 8; o <<= 1) ex += __shfl_xor(ex, o);
    const float lg = m + __logf(ex);

    float4 r0, r1;
    r0.x = v[0] - lg; r0.y = v[1] - lg; r0.z = v[2] - lg; r0.w = v[3] - lg;
    r1.x = v[4] - lg; r1.y = v[5] - lg; r1.z = v[6] - lg; r1.w = v[7] - lg;
    float4* o4 = reinterpret_cast<float4*>(out + (size_t)node * NCLS);
    o4[li * 2] = r0;
    o4[li * 2 + 1] = r1;
}

extern "C" void kernel_launch(void* const* d_in, const int* in_sizes, int n_in,
                              void* d_out, int out_size, void* d_ws, size_t ws_size,
                              hipStream_t stream) {
    const float* x = (const float*)d_in[0];       // [N, 512]
    const float* W = (const float*)d_in[1];       // [512, 64]
    const float* b = (const float*)d_in[2];       // [64]
    const int* edge_index = (const int*)d_in[3];  // [2, E]

    const int N = in_sizes[0] / F_IN;
    const int E = in_sizes[3] / 2;
    const int* src = edge_index;
    const int* dst = edge_index + E;

    float* out = (float*)d_out;  // [N, 64]

    // workspace layout (16B-aligned pieces first)
    char* ws = (char*)d_ws;
    short* g     = (short*)ws;  ws += (size_t)N * NCLS * 2;   // 12.8 MB bf16
    short* Wb    = (short*)ws;  ws += 4096 * 16;              // 64 KB
    float* dinv  = (float*)ws;  ws += (size_t)N * 4;
    int*   cnt   = (int*)ws;    ws += (size_t)N * 4;
    int*   off   = (int*)ws;    ws += (size_t)(N + 4) * 4;
    int*   parts = (int*)ws;    ws += 1024 * 4;
    unsigned short* rank = (unsigned short*)ws;  ws += (size_t)((E + 7) & ~7) * 2;  // 3.2 MB
    int*   eidx  = (int*)ws;    // E ints

    const int nScanBlocks = (N + SCAN_BLK - 1) / SCAN_BLK;
    const int gemmBlocks = (N + 63) / 64;
    const int degBlocks = (E + 1023) / 1024;

    prelude<<<16 + (N + 255) / 256, 256, 0, stream>>>(W, Wb, cnt, N);

    megaA<<<gemmBlocks + degBlocks, 256, 0, stream>>>(x, Wb, g, N, dst, cnt, rank, E,
                                                      gemmBlocks, degBlocks);

    scan1<<<nScanBlocks, SCAN_BLK, 0, stream>>>(cnt, off, parts, dinv, N);
    scan2<<<1, 256, 0, stream>>>(parts, nScanBlocks);

    fill_csr<<<degBlocks, 256, 0, stream>>>(src, dst, off, parts, rank, eidx, E);

    aggregate<<<(N + 31) / 32, 256, 0, stream>>>(g, dinv, b, off, parts, eidx, out, N);
}